// Round 4
// baseline (410.409 us; speedup 1.0000x reference)
//
#include <hip/hip_runtime.h>
#include <hip/hip_bf16.h>
#include <math.h>

#define B1 2048
#define B2 8192
#define NH 12
#define DH 64
#define DMODEL 768

typedef __attribute__((ext_vector_type(8))) short short8;
typedef __attribute__((ext_vector_type(4))) float floatx4;
typedef __attribute__((ext_vector_type(8))) unsigned short ushort8;
typedef __attribute__((ext_vector_type(4))) unsigned short ushort4v;

static __device__ __forceinline__ unsigned short f2bf(float f) {
  __bf16 b = (__bf16)f;
  return __builtin_bit_cast(unsigned short, b);
}
static __device__ __forceinline__ float bf2f(unsigned short u) {
  return __builtin_bit_cast(float, ((unsigned)u) << 16);
}

// ---------------------------------------------------------------------------
// MFMA GEMM NT: C[M,N] = A[M,K]*B[N,K]^T, fp32 inputs converted to bf16.
// 128x128 tile, BK=32, 256 threads = 4 waves (2x2), 64x64 per wave.
// SPLIT: two-sided bf16 hi/lo split (3 MFMAs/k-step) => ~fp32 precision.
// L2N:   per-64-column L2 normalization epilogue (per-head cosine norm).
// ---------------------------------------------------------------------------
#define TSTR 40

template <bool SPLIT, bool L2N, bool F32OUT>
__global__ __launch_bounds__(256) void gemm_mfma(const float* __restrict__ A,
                                                 const float* __restrict__ B,
                                                 void* __restrict__ Cv,
                                                 int M, int N, int K) {
  __shared__ unsigned short Ah[128 * TSTR];
  __shared__ unsigned short Bh[128 * TSTR];
  __shared__ unsigned short Al[SPLIT ? 128 * TSTR : 8];
  __shared__ unsigned short Bl[SPLIT ? 128 * TSTR : 8];

  const int tid = threadIdx.x;
  const int m0 = blockIdx.y * 128;
  const int n0 = blockIdx.x * 128;
  const int wave = tid >> 6;
  const int lane = tid & 63;
  const int wm = wave >> 1;
  const int wn = wave & 1;
  const int n15 = lane & 15;
  const int quad = lane >> 4;

  floatx4 acc[4][4];
#pragma unroll
  for (int i = 0; i < 4; ++i)
#pragma unroll
    for (int j = 0; j < 4; ++j) acc[i][j] = (floatx4){0.f, 0.f, 0.f, 0.f};

  for (int k0 = 0; k0 < K; k0 += 32) {
    __syncthreads();
#pragma unroll
    for (int i = 0; i < 4; ++i) {
      const int slot = i * 256 + tid;
      const int rr = slot >> 3;
      const int cc = (slot & 7) << 2;
      const float4 a4 = *(const float4*)&A[(size_t)(m0 + rr) * K + k0 + cc];
      const float4 b4 = *(const float4*)&B[(size_t)(n0 + rr) * K + k0 + cc];
      ushort4v ah = {f2bf(a4.x), f2bf(a4.y), f2bf(a4.z), f2bf(a4.w)};
      ushort4v bh = {f2bf(b4.x), f2bf(b4.y), f2bf(b4.z), f2bf(b4.w)};
      *(ushort4v*)&Ah[rr * TSTR + cc] = ah;
      *(ushort4v*)&Bh[rr * TSTR + cc] = bh;
      if constexpr (SPLIT) {
        ushort4v al = {f2bf(a4.x - bf2f(ah[0])), f2bf(a4.y - bf2f(ah[1])),
                       f2bf(a4.z - bf2f(ah[2])), f2bf(a4.w - bf2f(ah[3]))};
        ushort4v bl = {f2bf(b4.x - bf2f(bh[0])), f2bf(b4.y - bf2f(bh[1])),
                       f2bf(b4.z - bf2f(bh[2])), f2bf(b4.w - bf2f(bh[3]))};
        *(ushort4v*)&Al[rr * TSTR + cc] = al;
        *(ushort4v*)&Bl[rr * TSTR + cc] = bl;
      }
    }
    __syncthreads();

    short8 afh[4], afl[4];
#pragma unroll
    for (int mt = 0; mt < 4; ++mt) {
      const int arow = wm * 64 + mt * 16 + n15;
      afh[mt] = *(const short8*)&Ah[arow * TSTR + quad * 8];
      if constexpr (SPLIT) afl[mt] = *(const short8*)&Al[arow * TSTR + quad * 8];
    }
#pragma unroll
    for (int nt = 0; nt < 4; ++nt) {
      const int brow = wn * 64 + nt * 16 + n15;
      const short8 bfh = *(const short8*)&Bh[brow * TSTR + quad * 8];
      if constexpr (SPLIT) {
        const short8 bfl = *(const short8*)&Bl[brow * TSTR + quad * 8];
#pragma unroll
        for (int mt = 0; mt < 4; ++mt) {
          acc[mt][nt] = __builtin_amdgcn_mfma_f32_16x16x32_bf16(afh[mt], bfh, acc[mt][nt], 0, 0, 0);
          acc[mt][nt] = __builtin_amdgcn_mfma_f32_16x16x32_bf16(afh[mt], bfl, acc[mt][nt], 0, 0, 0);
          acc[mt][nt] = __builtin_amdgcn_mfma_f32_16x16x32_bf16(afl[mt], bfh, acc[mt][nt], 0, 0, 0);
        }
      } else {
#pragma unroll
        for (int mt = 0; mt < 4; ++mt)
          acc[mt][nt] = __builtin_amdgcn_mfma_f32_16x16x32_bf16(afh[mt], bfh, acc[mt][nt], 0, 0, 0);
      }
    }
  }

#pragma unroll
  for (int mt = 0; mt < 4; ++mt) {
    float scalev[4] = {1.f, 1.f, 1.f, 1.f};
    if constexpr (L2N) {
#pragma unroll
      for (int rr = 0; rr < 4; ++rr) {
        float ss = 0.f;
#pragma unroll
        for (int nt = 0; nt < 4; ++nt) ss += acc[mt][nt][rr] * acc[mt][nt][rr];
        ss += __shfl_xor(ss, 1, 64);
        ss += __shfl_xor(ss, 2, 64);
        ss += __shfl_xor(ss, 4, 64);
        ss += __shfl_xor(ss, 8, 64);
        scalev[rr] = 1.0f / fmaxf(sqrtf(ss), 1e-12f);
      }
    }
#pragma unroll
    for (int nt = 0; nt < 4; ++nt) {
#pragma unroll
      for (int rr = 0; rr < 4; ++rr) {
        const int row = m0 + wm * 64 + mt * 16 + quad * 4 + rr;
        const int col = n0 + wn * 64 + nt * 16 + n15;
        const float v = acc[mt][nt][rr] * scalev[rr];
        if constexpr (F32OUT)
          ((float*)Cv)[(size_t)row * N + col] = v;
        else
          ((unsigned short*)Cv)[(size_t)row * N + col] = f2bf(v);
      }
    }
  }
}

// ---------------------------------------------------------------------------
// MFMA bf16 attention, occupancy-optimized.
// Fixed softmax max = invt (cos<=1): no rescaling, partials additive.
// Block: 1 head, 64 queries, 4 waves (qsub x ksub). KC=64 keys/chunk,
// KSPLIT=4 (grid 1536 = 6 blocks/CU target). LDS 25.6 KB, XOR-swizzled
// (chunk ^ row&7) dense K/V layouts: conflict-free b128 reads, no padding.
// QK^T computed TRANSPOSED (S^T = K*Q^T) so P exits with 4 consecutive
// keys per lane -> packed ds_write_b64 instead of 32 scalar b16 writes.
// ---------------------------------------------------------------------------
#define KC 64
#define KSPLIT 4
#define PSTR 36

__global__ __launch_bounds__(256, 5) void attn_mfma(
    const unsigned short* __restrict__ qb,   // [B1][768] bf16, normalized
    const unsigned short* __restrict__ kb,   // [B2][768] bf16, normalized
    const unsigned short* __restrict__ vt,   // [768][B2] bf16 (v transposed)
    float* __restrict__ aoacc,               // [B1][768] f32, zeroed
    float* __restrict__ lacc,                // [B1][NH] f32, zeroed
    const int* __restrict__ invt_p) {
  // one contiguous LDS pool; Osc epilogue aliases Kl+Vl (16 KB)
  __shared__ __align__(16) unsigned short smem[12800];
  unsigned short* Kl = smem;          // [64 keys][64 d], swizzled, 8192 B
  unsigned short* Vl = smem + 4096;   // [64 d][64 keys], swizzled, 8192 B
  unsigned short* Psl = smem + 8192;  // 4 waves x [32 q][PSTR], 9216 B

  const float c2 = (float)invt_p[0] * 1.4426950408889634f;  // invt*log2(e)
  const int h = blockIdx.y;
  const int q0 = blockIdx.x * 64;
  const int tid = threadIdx.x;
  const int wave = tid >> 6;
  const int lane = tid & 63;
  const int qsub = wave >> 1;
  const int ksub = wave & 1;
  const int n15 = lane & 15;
  const int quad = lane >> 4;
  const int kz0 = blockIdx.z * (B2 / KSPLIT);

  unsigned short* Ps = &Psl[wave * 32 * PSTR];

  // Q B-fragments (S^T = K*Q^T): lane holds Q[q = qt*16+n15][d = ks*32+quad*8..]
  short8 qf[2][2];
#pragma unroll
  for (int qt = 0; qt < 2; ++qt)
#pragma unroll
    for (int ks = 0; ks < 2; ++ks) {
      const int qrow = q0 + qsub * 32 + qt * 16 + n15;
      qf[qt][ks] = *(const short8*)&qb[(size_t)qrow * DMODEL + h * DH + ks * 32 + quad * 8];
    }

  floatx4 oacc[2][4];
#pragma unroll
  for (int qt = 0; qt < 2; ++qt)
#pragma unroll
    for (int nt = 0; nt < 4; ++nt) oacc[qt][nt] = (floatx4){0.f, 0.f, 0.f, 0.f};
  float lsum[2] = {0.f, 0.f};

  for (int c = 0; c < B2 / KSPLIT; c += KC) {
    const int kc0 = kz0 + c;
    __syncthreads();  // previous chunk's LDS reads complete
    // stage K: 64 keys x 128B (512 slots of 16B), V^T: 64 d x 128B
#pragma unroll
    for (int i = 0; i < 4; ++i) {
      const int s = i * 256 + tid;
      if (i < 2) {
        const int key = s >> 3, cp = s & 7, ch = cp ^ (key & 7);
        const ushort8 t = *(const ushort8*)&kb[(size_t)(kc0 + key) * DMODEL + h * DH + ch * 8];
        *(ushort8*)&Kl[key * 64 + cp * 8] = t;
      } else {
        const int s2 = s - 512;
        const int d = s2 >> 3, cp = s2 & 7, ch = cp ^ (d & 7);
        const ushort8 t = *(const ushort8*)&vt[(size_t)(h * DH + d) * B2 + kc0 + ch * 8];
        *(ushort8*)&Vl[d * 64 + cp * 8] = t;
      }
    }
    __syncthreads();

    // S^T = K*Q^T -> exp -> P (bf16, wave-private, packed b64 stores)
#pragma unroll
    for (int kt = 0; kt < 2; ++kt) {
      floatx4 s0 = {0.f, 0.f, 0.f, 0.f}, s1 = {0.f, 0.f, 0.f, 0.f};
#pragma unroll
      for (int ks = 0; ks < 2; ++ks) {
        const int key = ksub * 32 + kt * 16 + n15;
        const int cp = (ks * 4 + quad) ^ (n15 & 7);
        const short8 kf = *(const short8*)&Kl[key * 64 + cp * 8];
        s0 = __builtin_amdgcn_mfma_f32_16x16x32_bf16(kf, qf[0][ks], s0, 0, 0, 0);
        s1 = __builtin_amdgcn_mfma_f32_16x16x32_bf16(kf, qf[1][ks], s1, 0, 0, 0);
      }
      // lane holds S^T[key = kt*16+quad*4+r][q = qt*16+n15]
      ushort4v p0, p1;
#pragma unroll
      for (int r = 0; r < 4; ++r) {
        const float e0 = exp2f(fmaf(s0[r], c2, -c2));
        const float e1 = exp2f(fmaf(s1[r], c2, -c2));
        lsum[0] += e0;
        lsum[1] += e1;
        p0[r] = f2bf(e0);
        p1[r] = f2bf(e1);
      }
      *(ushort4v*)&Ps[(0 * 16 + n15) * PSTR + kt * 16 + quad * 4] = p0;
      *(ushort4v*)&Ps[(1 * 16 + n15) * PSTR + kt * 16 + quad * 4] = p1;
    }
    // (no barrier: Ps wave-private; in-wave lgkmcnt ordering by compiler)

    // O += P[32q x 32k] * V[32k x 64d]
    short8 pa[2];
#pragma unroll
    for (int qt = 0; qt < 2; ++qt)
      pa[qt] = *(const short8*)&Ps[(qt * 16 + n15) * PSTR + quad * 8];
#pragma unroll
    for (int nt = 0; nt < 4; ++nt) {
      const int dd = nt * 16 + n15;
      const int cp = (ksub * 4 + quad) ^ (n15 & 7);
      const short8 vf = *(const short8*)&Vl[dd * 64 + cp * 8];
      oacc[0][nt] = __builtin_amdgcn_mfma_f32_16x16x32_bf16(pa[0], vf, oacc[0][nt], 0, 0, 0);
      oacc[1][nt] = __builtin_amdgcn_mfma_f32_16x16x32_bf16(pa[1], vf, oacc[1][nt], 0, 0, 0);
    }
  }

  // lsum: lane has partial for q = qt*16+n15 over its keys; reduce across quads
#pragma unroll
  for (int qt = 0; qt < 2; ++qt) {
    float v = lsum[qt];
    v += __shfl_xor(v, 16, 64);
    v += __shfl_xor(v, 32, 64);
    lsum[qt] = v;
  }
  if (quad == 0) {
#pragma unroll
    for (int qt = 0; qt < 2; ++qt)
      atomicAdd(&lacc[(q0 + qsub * 32 + qt * 16 + n15) * NH + h], lsum[qt]);
  }

  // combine ksub pair via LDS (alias Kl+Vl as 64x64 f32), then global atomic
  __syncthreads();
  float* Osc = (float*)smem;
  if (ksub == 1) {
#pragma unroll
    for (int qt = 0; qt < 2; ++qt)
#pragma unroll
      for (int nt = 0; nt < 4; ++nt)
#pragma unroll
        for (int r = 0; r < 4; ++r) {
          const int row = qsub * 32 + qt * 16 + quad * 4 + r;
          Osc[row * 64 + nt * 16 + n15] = oacc[qt][nt][r];
        }
  }
  __syncthreads();
  if (ksub == 0) {
#pragma unroll
    for (int qt = 0; qt < 2; ++qt)
#pragma unroll
      for (int nt = 0; nt < 4; ++nt)
#pragma unroll
        for (int r = 0; r < 4; ++r) {
          const int row = qsub * 32 + qt * 16 + quad * 4 + r;
          const float v = oacc[qt][nt][r] + Osc[row * 64 + nt * 16 + n15];
          atomicAdd(&aoacc[(size_t)(q0 + row) * DMODEL + h * DH + nt * 16 + n15], v);
        }
  }
}

// ---------------------------------------------------------------------------
__global__ __launch_bounds__(256) void ao_normalize(const float* __restrict__ ao,
                                                    const float* __restrict__ l,
                                                    float* __restrict__ out) {
  const int row = blockIdx.x;
  const int t = threadIdx.x;
#pragma unroll
  for (int i = 0; i < 3; ++i) {
    const int d = t + i * 256;
    out[(size_t)row * DMODEL + d] =
        ao[(size_t)row * DMODEL + d] / l[row * NH + (d >> 6)];
  }
}

// ---------------------------------------------------------------------------
__global__ __launch_bounds__(256) void l2norm_rows768_out(
    const float* __restrict__ x, float* __restrict__ out) {
  const int row = blockIdx.x;
  const float* xr = &x[(size_t)row * DMODEL];
  float ss = 0.0f;
  float vals[3];
#pragma unroll
  for (int i = 0; i < 3; ++i) {
    vals[i] = xr[threadIdx.x + i * 256];
    ss += vals[i] * vals[i];
  }
#pragma unroll
  for (int off = 32; off > 0; off >>= 1) ss += __shfl_xor(ss, off, 64);
  __shared__ float ws[4];
  if ((threadIdx.x & 63) == 0) ws[threadIdx.x >> 6] = ss;
  __syncthreads();
  const float tot = ws[0] + ws[1] + ws[2] + ws[3];
  const float sc = 1.0f / fmaxf(sqrtf(tot), 1e-12f);
  float* orow = &out[(size_t)row * DMODEL];
#pragma unroll
  for (int i = 0; i < 3; ++i) orow[threadIdx.x + i * 256] = vals[i] * sc;
}

// ---------------------------------------------------------------------------
extern "C" void kernel_launch(void* const* d_in, const int* in_sizes, int n_in,
                              void* d_out, int out_size, void* d_ws,
                              size_t ws_size, hipStream_t stream) {
  const float* x1 = (const float*)d_in[0];
  const float* x2 = (const float*)d_in[1];
  const float* Wq = (const float*)d_in[2];
  const float* Wk = (const float*)d_in[3];
  const float* Wv = (const float*)d_in[4];
  const float* Wo = (const float*)d_in[5];
  const int* invt = (const int*)d_in[6];
  float* outp = (float*)d_out;

  char* ws = (char*)d_ws;
  unsigned short* q_bf = (unsigned short*)(ws);                      // 3145728 B
  unsigned short* k_bf = (unsigned short*)(ws + 3145728);            // 12582912 B
  unsigned short* vt_bf = (unsigned short*)(ws + 15728640);          // 12582912 B
  float* aoacc = (float*)(ws + 28311552);                            // 6291456 B
  float* lacc = (float*)(ws + 34603008);                             // 98304 B
  float* aonorm = (float*)(ws + 34701312);                           // 6291456 B
  float* woout = (float*)(ws + 40992768);                            // 6291456 B

  // q/k projections: split-precision MFMA + fused per-head l2norm, bf16 out
  gemm_mfma<true, true, false><<<dim3(DMODEL / 128, B1 / 128), 256, 0, stream>>>(
      x1, Wq, q_bf, B1, DMODEL, DMODEL);
  gemm_mfma<true, true, false><<<dim3(DMODEL / 128, B2 / 128), 256, 0, stream>>>(
      x2, Wk, k_bf, B2, DMODEL, DMODEL);
  // v projection, produced transposed: vt = Wv @ x2^T, plain bf16 MFMA
  gemm_mfma<false, false, false><<<dim3(B2 / 128, DMODEL / 128), 256, 0, stream>>>(
      Wv, x2, vt_bf, DMODEL, B2, DMODEL);
  // zero accumulators (ws is poisoned each call)
  hipMemsetAsync(aoacc, 0, (size_t)B1 * DMODEL * sizeof(float), stream);
  hipMemsetAsync(lacc, 0, (size_t)B1 * NH * sizeof(float), stream);
  // attention (MFMA bf16)
  attn_mfma<<<dim3(B1 / 64, NH, KSPLIT), 256, 0, stream>>>(q_bf, k_bf, vt_bf,
                                                           aoacc, lacc, invt);
  ao_normalize<<<B1, 256, 0, stream>>>(aoacc, lacc, aonorm);
  // output projection: plain bf16 MFMA, f32 out
  gemm_mfma<false, false, true><<<dim3(DMODEL / 128, B1 / 128), 256, 0, stream>>>(
      aonorm, Wo, woout, B1, DMODEL, DMODEL);
  l2norm_rows768_out<<<B1, 256, 0, stream>>>(woout, outp);
}

// Round 5
// 362.574 us; speedup vs baseline: 1.1319x; 1.1319x over previous
//
#include <hip/hip_runtime.h>
#include <hip/hip_bf16.h>
#include <math.h>

#define B1 2048
#define B2 8192
#define NH 12
#define DH 64
#define DMODEL 768

typedef __attribute__((ext_vector_type(8))) short short8;
typedef __attribute__((ext_vector_type(4))) float floatx4;
typedef __attribute__((ext_vector_type(8))) unsigned short ushort8;
typedef __attribute__((ext_vector_type(4))) unsigned short ushort4v;

static __device__ __forceinline__ unsigned short f2bf(float f) {
  __bf16 b = (__bf16)f;
  return __builtin_bit_cast(unsigned short, b);
}
static __device__ __forceinline__ float bf2f(unsigned short u) {
  return __builtin_bit_cast(float, ((unsigned)u) << 16);
}

// ---------------------------------------------------------------------------
// MFMA GEMM NT: C[M,N] = A[M,K]*B[N,K]^T, fp32 inputs converted to bf16.
// 128x128 tile, BK=32, 256 threads = 4 waves (2x2), 64x64 per wave.
// SPLIT: two-sided bf16 hi/lo split (3 MFMAs/k-step) => ~fp32 precision.
// L2N:   per-64-column L2 normalization epilogue (per-head cosine norm).
// ---------------------------------------------------------------------------
#define TSTR 40

template <bool SPLIT, bool L2N, bool F32OUT>
__global__ __launch_bounds__(256) void gemm_mfma(const float* __restrict__ A,
                                                 const float* __restrict__ B,
                                                 void* __restrict__ Cv,
                                                 int M, int N, int K) {
  __shared__ unsigned short Ah[128 * TSTR];
  __shared__ unsigned short Bh[128 * TSTR];
  __shared__ unsigned short Al[SPLIT ? 128 * TSTR : 8];
  __shared__ unsigned short Bl[SPLIT ? 128 * TSTR : 8];

  const int tid = threadIdx.x;
  const int m0 = blockIdx.y * 128;
  const int n0 = blockIdx.x * 128;
  const int wave = tid >> 6;
  const int lane = tid & 63;
  const int wm = wave >> 1;
  const int wn = wave & 1;
  const int n15 = lane & 15;
  const int quad = lane >> 4;

  floatx4 acc[4][4];
#pragma unroll
  for (int i = 0; i < 4; ++i)
#pragma unroll
    for (int j = 0; j < 4; ++j) acc[i][j] = (floatx4){0.f, 0.f, 0.f, 0.f};

  for (int k0 = 0; k0 < K; k0 += 32) {
    __syncthreads();
#pragma unroll
    for (int i = 0; i < 4; ++i) {
      const int slot = i * 256 + tid;
      const int rr = slot >> 3;
      const int cc = (slot & 7) << 2;
      const float4 a4 = *(const float4*)&A[(size_t)(m0 + rr) * K + k0 + cc];
      const float4 b4 = *(const float4*)&B[(size_t)(n0 + rr) * K + k0 + cc];
      ushort4v ah = {f2bf(a4.x), f2bf(a4.y), f2bf(a4.z), f2bf(a4.w)};
      ushort4v bh = {f2bf(b4.x), f2bf(b4.y), f2bf(b4.z), f2bf(b4.w)};
      *(ushort4v*)&Ah[rr * TSTR + cc] = ah;
      *(ushort4v*)&Bh[rr * TSTR + cc] = bh;
      if constexpr (SPLIT) {
        ushort4v al = {f2bf(a4.x - bf2f(ah[0])), f2bf(a4.y - bf2f(ah[1])),
                       f2bf(a4.z - bf2f(ah[2])), f2bf(a4.w - bf2f(ah[3]))};
        ushort4v bl = {f2bf(b4.x - bf2f(bh[0])), f2bf(b4.y - bf2f(bh[1])),
                       f2bf(b4.z - bf2f(bh[2])), f2bf(b4.w - bf2f(bh[3]))};
        *(ushort4v*)&Al[rr * TSTR + cc] = al;
        *(ushort4v*)&Bl[rr * TSTR + cc] = bl;
      }
    }
    __syncthreads();

    short8 afh[4], afl[4];
#pragma unroll
    for (int mt = 0; mt < 4; ++mt) {
      const int arow = wm * 64 + mt * 16 + n15;
      afh[mt] = *(const short8*)&Ah[arow * TSTR + quad * 8];
      if constexpr (SPLIT) afl[mt] = *(const short8*)&Al[arow * TSTR + quad * 8];
    }
#pragma unroll
    for (int nt = 0; nt < 4; ++nt) {
      const int brow = wn * 64 + nt * 16 + n15;
      const short8 bfh = *(const short8*)&Bh[brow * TSTR + quad * 8];
      if constexpr (SPLIT) {
        const short8 bfl = *(const short8*)&Bl[brow * TSTR + quad * 8];
#pragma unroll
        for (int mt = 0; mt < 4; ++mt) {
          acc[mt][nt] = __builtin_amdgcn_mfma_f32_16x16x32_bf16(afh[mt], bfh, acc[mt][nt], 0, 0, 0);
          acc[mt][nt] = __builtin_amdgcn_mfma_f32_16x16x32_bf16(afh[mt], bfl, acc[mt][nt], 0, 0, 0);
          acc[mt][nt] = __builtin_amdgcn_mfma_f32_16x16x32_bf16(afl[mt], bfh, acc[mt][nt], 0, 0, 0);
        }
      } else {
#pragma unroll
        for (int mt = 0; mt < 4; ++mt)
          acc[mt][nt] = __builtin_amdgcn_mfma_f32_16x16x32_bf16(afh[mt], bfh, acc[mt][nt], 0, 0, 0);
      }
    }
  }

#pragma unroll
  for (int mt = 0; mt < 4; ++mt) {
    float scalev[4] = {1.f, 1.f, 1.f, 1.f};
    if constexpr (L2N) {
#pragma unroll
      for (int rr = 0; rr < 4; ++rr) {
        float ss = 0.f;
#pragma unroll
        for (int nt = 0; nt < 4; ++nt) ss += acc[mt][nt][rr] * acc[mt][nt][rr];
        ss += __shfl_xor(ss, 1, 64);
        ss += __shfl_xor(ss, 2, 64);
        ss += __shfl_xor(ss, 4, 64);
        ss += __shfl_xor(ss, 8, 64);
        scalev[rr] = 1.0f / fmaxf(sqrtf(ss), 1e-12f);
      }
    }
#pragma unroll
    for (int nt = 0; nt < 4; ++nt) {
#pragma unroll
      for (int rr = 0; rr < 4; ++rr) {
        const int row = m0 + wm * 64 + mt * 16 + quad * 4 + rr;
        const int col = n0 + wn * 64 + nt * 16 + n15;
        const float v = acc[mt][nt][rr] * scalev[rr];
        if constexpr (F32OUT)
          ((float*)Cv)[(size_t)row * N + col] = v;
        else
          ((unsigned short*)Cv)[(size_t)row * N + col] = f2bf(v);
      }
    }
  }
}

// ---------------------------------------------------------------------------
// MFMA bf16 attention with REGISTER-PREFETCH software pipeline.
// Fixed softmax max = invt (cos<=1): no rescaling, partials additive.
// Block: 1 head, 64 queries, 4 waves (qsub x ksub), KC=128 keys/chunk,
// KSPLIT=2 (grid 768 = 3 blocks/CU, one full round). LDS ~50 KB swizzled
// dense (conflict-free b128). Pipeline: write prefetched regs->LDS, issue
// NEXT chunk's global loads (VGPR dest - no vmcnt drain at barrier),
// barrier, compute. Loads for c+1 overlap compute of c.
// S^T = K*Q^T so P exits with 4 consecutive keys/lane (packed b64 stores).
// ---------------------------------------------------------------------------
#define KC 128
#define KSPLIT 2
#define NCH (B2 / KSPLIT / KC)  // 32
#define PSTR 68

__global__ __launch_bounds__(256, 3) void attn_mfma(
    const unsigned short* __restrict__ qb,   // [B1][768] bf16, normalized
    const unsigned short* __restrict__ kb,   // [B2][768] bf16, normalized
    const unsigned short* __restrict__ vt,   // [768][B2] bf16 (v transposed)
    float* __restrict__ aoacc,               // [B1][768] f32, zeroed
    float* __restrict__ lacc,                // [B1][NH] f32, zeroed
    const int* __restrict__ invt_p) {
  __shared__ __align__(16) unsigned short smem[25088];  // 50176 B
  unsigned short* Kl = smem;            // [128 keys][64 d] swizzled, 16 KB
  unsigned short* Vl = smem + 8192;     // [64 d][128 keys] swizzled, 16 KB
  unsigned short* Psl = smem + 16384;   // 4 waves x [32 q][PSTR], 17.4 KB

  const float c2 = (float)invt_p[0] * 1.4426950408889634f;  // invt*log2(e)
  const int h = blockIdx.y;
  const int q0 = blockIdx.x * 64;
  const int tid = threadIdx.x;
  const int wave = tid >> 6;
  const int lane = tid & 63;
  const int qsub = wave >> 1;
  const int ksub = wave & 1;
  const int n15 = lane & 15;
  const int quad = lane >> 4;
  const int kz0 = blockIdx.z * (B2 / KSPLIT);

  unsigned short* Ps = &Psl[wave * 32 * PSTR];

  // Q B-fragments: lane holds Q[q = qt*16+n15][d = ks*32+quad*8..]
  short8 qf[2][2];
#pragma unroll
  for (int qt = 0; qt < 2; ++qt)
#pragma unroll
    for (int ks = 0; ks < 2; ++ks) {
      const int qrow = q0 + qsub * 32 + qt * 16 + n15;
      qf[qt][ks] = *(const short8*)&qb[(size_t)qrow * DMODEL + h * DH + ks * 32 + quad * 8];
    }

  floatx4 oacc[2][4];
#pragma unroll
  for (int qt = 0; qt < 2; ++qt)
#pragma unroll
    for (int nt = 0; nt < 4; ++nt) oacc[qt][nt] = (floatx4){0.f, 0.f, 0.f, 0.f};
  float lsum[2] = {0.f, 0.f};

  // staging slot decode (reused): K slot s: key=s>>3, cp=s&7, ch=cp^(key&7)
  //                               V slot s: d=s>>4, cp=s&15, ch=cp^(d&15)
  ushort8 kr[4], vr[4];
#pragma unroll
  for (int i = 0; i < 4; ++i) {
    const int s = i * 256 + tid;
    const int key = s >> 3, cpk = s & 7, chk = cpk ^ (key & 7);
    kr[i] = *(const ushort8*)&kb[(size_t)(kz0 + key) * DMODEL + h * DH + chk * 8];
    const int d = s >> 4, cpv = s & 15, chv = cpv ^ (d & 15);
    vr[i] = *(const ushort8*)&vt[(size_t)(h * DH + d) * B2 + kz0 + chv * 8];
  }

  for (int c = 0; c < NCH; ++c) {
    __syncthreads();  // previous chunk's LDS reads complete
    // regs -> LDS (waits the in-flight loads here, not at the barrier)
#pragma unroll
    for (int i = 0; i < 4; ++i) {
      const int s = i * 256 + tid;
      const int key = s >> 3, cpk = s & 7;
      *(ushort8*)&Kl[key * 64 + cpk * 8] = kr[i];
      const int d = s >> 4, cpv = s & 15;
      *(ushort8*)&Vl[d * 128 + cpv * 8] = vr[i];
    }
    // issue next chunk's loads (overlap with compute below)
    if (c + 1 < NCH) {
      const int kc0n = kz0 + (c + 1) * KC;
#pragma unroll
      for (int i = 0; i < 4; ++i) {
        const int s = i * 256 + tid;
        const int key = s >> 3, cpk = s & 7, chk = cpk ^ (key & 7);
        kr[i] = *(const ushort8*)&kb[(size_t)(kc0n + key) * DMODEL + h * DH + chk * 8];
        const int d = s >> 4, cpv = s & 15, chv = cpv ^ (d & 15);
        vr[i] = *(const ushort8*)&vt[(size_t)(h * DH + d) * B2 + kc0n + chv * 8];
      }
    }
    __syncthreads();

    // S^T = K*Q^T over wave's 64 keys -> exp -> P (packed b64 stores)
#pragma unroll
    for (int kt = 0; kt < 4; ++kt) {
      floatx4 s0 = {0.f, 0.f, 0.f, 0.f}, s1 = {0.f, 0.f, 0.f, 0.f};
#pragma unroll
      for (int ks = 0; ks < 2; ++ks) {
        const int key = ksub * 64 + kt * 16 + n15;
        const int cp = (ks * 4 + quad) ^ (n15 & 7);
        const short8 kf = *(const short8*)&Kl[key * 64 + cp * 8];
        s0 = __builtin_amdgcn_mfma_f32_16x16x32_bf16(kf, qf[0][ks], s0, 0, 0, 0);
        s1 = __builtin_amdgcn_mfma_f32_16x16x32_bf16(kf, qf[1][ks], s1, 0, 0, 0);
      }
      ushort4v p0, p1;
#pragma unroll
      for (int r = 0; r < 4; ++r) {
        const float e0 = exp2f(fmaf(s0[r], c2, -c2));
        const float e1 = exp2f(fmaf(s1[r], c2, -c2));
        lsum[0] += e0;
        lsum[1] += e1;
        p0[r] = f2bf(e0);
        p1[r] = f2bf(e1);
      }
      *(ushort4v*)&Ps[(0 * 16 + n15) * PSTR + kt * 16 + quad * 4] = p0;
      *(ushort4v*)&Ps[(1 * 16 + n15) * PSTR + kt * 16 + quad * 4] = p1;
    }
    // (no barrier: Ps wave-private)

    // O[32q x 64d] += P[32q x 64k] * V[64k x 64d]
#pragma unroll
    for (int ks = 0; ks < 2; ++ks) {
      short8 pa[2];
#pragma unroll
      for (int qt = 0; qt < 2; ++qt)
        pa[qt] = *(const short8*)&Ps[(qt * 16 + n15) * PSTR + ks * 32 + quad * 8];
#pragma unroll
      for (int nt = 0; nt < 4; ++nt) {
        const int dd = nt * 16 + n15;
        const int cp = (ksub * 8 + ks * 4 + quad) ^ (n15 & 15);
        const short8 vf = *(const short8*)&Vl[dd * 128 + cp * 8];
        oacc[0][nt] = __builtin_amdgcn_mfma_f32_16x16x32_bf16(pa[0], vf, oacc[0][nt], 0, 0, 0);
        oacc[1][nt] = __builtin_amdgcn_mfma_f32_16x16x32_bf16(pa[1], vf, oacc[1][nt], 0, 0, 0);
      }
    }
  }

  // lsum: lane has partial for q = qt*16+n15; reduce across quads
#pragma unroll
  for (int qt = 0; qt < 2; ++qt) {
    float v = lsum[qt];
    v += __shfl_xor(v, 16, 64);
    v += __shfl_xor(v, 32, 64);
    lsum[qt] = v;
  }
  if (quad == 0) {
#pragma unroll
    for (int qt = 0; qt < 2; ++qt)
      atomicAdd(&lacc[(q0 + qsub * 32 + qt * 16 + n15) * NH + h], lsum[qt]);
  }

  // combine ksub pair via LDS (alias Kl+Vl as 64x64 f32), then global atomic
  __syncthreads();
  float* Osc = (float*)smem;
  if (ksub == 1) {
#pragma unroll
    for (int qt = 0; qt < 2; ++qt)
#pragma unroll
      for (int nt = 0; nt < 4; ++nt)
#pragma unroll
        for (int r = 0; r < 4; ++r) {
          const int row = qsub * 32 + qt * 16 + quad * 4 + r;
          Osc[row * 64 + nt * 16 + n15] = oacc[qt][nt][r];
        }
  }
  __syncthreads();
  if (ksub == 0) {
#pragma unroll
    for (int qt = 0; qt < 2; ++qt)
#pragma unroll
      for (int nt = 0; nt < 4; ++nt)
#pragma unroll
        for (int r = 0; r < 4; ++r) {
          const int row = qsub * 32 + qt * 16 + quad * 4 + r;
          const float v = oacc[qt][nt][r] + Osc[row * 64 + nt * 16 + n15];
          atomicAdd(&aoacc[(size_t)(q0 + row) * DMODEL + h * DH + nt * 16 + n15], v);
        }
  }
}

// ---------------------------------------------------------------------------
__global__ __launch_bounds__(256) void ao_normalize(const float* __restrict__ ao,
                                                    const float* __restrict__ l,
                                                    float* __restrict__ out) {
  const int row = blockIdx.x;
  const int t = threadIdx.x;
#pragma unroll
  for (int i = 0; i < 3; ++i) {
    const int d = t + i * 256;
    out[(size_t)row * DMODEL + d] =
        ao[(size_t)row * DMODEL + d] / l[row * NH + (d >> 6)];
  }
}

// ---------------------------------------------------------------------------
__global__ __launch_bounds__(256) void l2norm_rows768_out(
    const float* __restrict__ x, float* __restrict__ out) {
  const int row = blockIdx.x;
  const float* xr = &x[(size_t)row * DMODEL];
  float ss = 0.0f;
  float vals[3];
#pragma unroll
  for (int i = 0; i < 3; ++i) {
    vals[i] = xr[threadIdx.x + i * 256];
    ss += vals[i] * vals[i];
  }
#pragma unroll
  for (int off = 32; off > 0; off >>= 1) ss += __shfl_xor(ss, off, 64);
  __shared__ float ws[4];
  if ((threadIdx.x & 63) == 0) ws[threadIdx.x >> 6] = ss;
  __syncthreads();
  const float tot = ws[0] + ws[1] + ws[2] + ws[3];
  const float sc = 1.0f / fmaxf(sqrtf(tot), 1e-12f);
  float* orow = &out[(size_t)row * DMODEL];
#pragma unroll
  for (int i = 0; i < 3; ++i) orow[threadIdx.x + i * 256] = vals[i] * sc;
}

// ---------------------------------------------------------------------------
extern "C" void kernel_launch(void* const* d_in, const int* in_sizes, int n_in,
                              void* d_out, int out_size, void* d_ws,
                              size_t ws_size, hipStream_t stream) {
  const float* x1 = (const float*)d_in[0];
  const float* x2 = (const float*)d_in[1];
  const float* Wq = (const float*)d_in[2];
  const float* Wk = (const float*)d_in[3];
  const float* Wv = (const float*)d_in[4];
  const float* Wo = (const float*)d_in[5];
  const int* invt = (const int*)d_in[6];
  float* outp = (float*)d_out;

  char* ws = (char*)d_ws;
  unsigned short* q_bf = (unsigned short*)(ws);                      // 3145728 B
  unsigned short* k_bf = (unsigned short*)(ws + 3145728);            // 12582912 B
  unsigned short* vt_bf = (unsigned short*)(ws + 15728640);          // 12582912 B
  float* aoacc = (float*)(ws + 28311552);                            // 6291456 B
  float* lacc = (float*)(ws + 34603008);                             // 98304 B
  float* aonorm = (float*)(ws + 34701312);                           // 6291456 B
  float* woout = (float*)(ws + 40992768);                            // 6291456 B

  // q/k projections: split-precision MFMA + fused per-head l2norm, bf16 out
  gemm_mfma<true, true, false><<<dim3(DMODEL / 128, B1 / 128), 256, 0, stream>>>(
      x1, Wq, q_bf, B1, DMODEL, DMODEL);
  gemm_mfma<true, true, false><<<dim3(DMODEL / 128, B2 / 128), 256, 0, stream>>>(
      x2, Wk, k_bf, B2, DMODEL, DMODEL);
  // v projection, produced transposed: vt = Wv @ x2^T, plain bf16 MFMA
  gemm_mfma<false, false, false><<<dim3(B2 / 128, DMODEL / 128), 256, 0, stream>>>(
      Wv, x2, vt_bf, DMODEL, B2, DMODEL);
  // zero accumulators (ws is poisoned each call)
  hipMemsetAsync(aoacc, 0, (size_t)B1 * DMODEL * sizeof(float), stream);
  hipMemsetAsync(lacc, 0, (size_t)B1 * NH * sizeof(float), stream);
  // attention (MFMA bf16, register-prefetch pipeline)
  attn_mfma<<<dim3(B1 / 64, NH, KSPLIT), 256, 0, stream>>>(q_bf, k_bf, vt_bf,
                                                           aoacc, lacc, invt);
  ao_normalize<<<B1, 256, 0, stream>>>(aoacc, lacc, aonorm);
  // output projection: plain bf16 MFMA, f32 out
  gemm_mfma<false, false, true><<<dim3(DMODEL / 128, B1 / 128), 256, 0, stream>>>(
      aonorm, Wo, woout, B1, DMODEL, DMODEL);
  l2norm_rows768_out<<<B1, 256, 0, stream>>>(woout, outp);
}

// Round 6
// 352.561 us; speedup vs baseline: 1.1641x; 1.0284x over previous
//
#include <hip/hip_runtime.h>
#include <hip/hip_bf16.h>
#include <math.h>

#define B1 2048
#define B2 8192
#define NH 12
#define DH 64
#define DMODEL 768

typedef __attribute__((ext_vector_type(8))) short short8;
typedef __attribute__((ext_vector_type(4))) float floatx4;
typedef __attribute__((ext_vector_type(8))) unsigned short ushort8;
typedef __attribute__((ext_vector_type(4))) unsigned short ushort4v;

static __device__ __forceinline__ unsigned short f2bf(float f) {
  __bf16 b = (__bf16)f;
  return __builtin_bit_cast(unsigned short, b);
}
static __device__ __forceinline__ float bf2f(unsigned short u) {
  return __builtin_bit_cast(float, ((unsigned)u) << 16);
}

// async global->LDS, 16B per lane; LDS dest = wave-uniform base + lane*16
static __device__ __forceinline__ void gload16(const unsigned short* g,
                                               unsigned short* l) {
  __builtin_amdgcn_global_load_lds(
      (const __attribute__((address_space(1))) void*)g,
      (__attribute__((address_space(3))) void*)l, 16, 0, 0);
}

// ---------------------------------------------------------------------------
// Prep: one-time fp32 -> bf16 hi(/lo) conversion (hoists all conversion VALU
// out of the GEMM K-loops). Memory-bound.
// ---------------------------------------------------------------------------
__global__ __launch_bounds__(256) void split_hl(const float* __restrict__ src,
                                                unsigned short* __restrict__ hi,
                                                unsigned short* __restrict__ lo,
                                                int n) {
  const int i = (blockIdx.x * 256 + threadIdx.x) * 4;
  if (i >= n) return;
  const float4 v = *(const float4*)&src[i];
  ushort4v h = {f2bf(v.x), f2bf(v.y), f2bf(v.z), f2bf(v.w)};
  *(ushort4v*)&hi[i] = h;
  ushort4v l = {f2bf(v.x - bf2f(h[0])), f2bf(v.y - bf2f(h[1])),
                f2bf(v.z - bf2f(h[2])), f2bf(v.w - bf2f(h[3]))};
  *(ushort4v*)&lo[i] = l;
}

__global__ __launch_bounds__(256) void cvt_h(const float* __restrict__ src,
                                             unsigned short* __restrict__ hi,
                                             int n) {
  const int i = (blockIdx.x * 256 + threadIdx.x) * 4;
  if (i >= n) return;
  const float4 v = *(const float4*)&src[i];
  ushort4v h = {f2bf(v.x), f2bf(v.y), f2bf(v.z), f2bf(v.w)};
  *(ushort4v*)&hi[i] = h;
}

// ---------------------------------------------------------------------------
// bf16 MFMA GEMM NT: C[M,N] = A[M,K]*B[N,K]^T, pre-converted bf16 inputs.
// 128x128 tile, BK=32 halves, 4 waves (2x2), 64x64/wave.
// Staging via global_load_lds dwordx4 (async, no VGPR round-trip). LDS layout:
// halfoff = row*32 + cpp*8 where phys granule cpp holds logical granule
// cpl = cpp ^ ((row>>2)&3)  (swizzle applied on the GLOBAL address so the
// lane*16 LDS-dest constraint is satisfied). Frag ds_read_b128 then lands as
// 2-way bank aliasing = free (m136).
// SPLIT: hi/lo operands, 3 MFMAs/k-step => ~fp32 precision.
// L2N: per-64-col (per-head) L2 norm epilogue. F32OUT: store f32.
// ---------------------------------------------------------------------------
template <bool SPLIT, bool L2N, bool F32OUT>
__global__ __launch_bounds__(256) void gemm_bf16_nt(
    const unsigned short* __restrict__ Ahg, const unsigned short* __restrict__ Alg,
    const unsigned short* __restrict__ Bhg, const unsigned short* __restrict__ Blg,
    void* __restrict__ Cv, int M, int N, int K) {
  __shared__ __align__(16) unsigned short sAh[128 * 32];
  __shared__ __align__(16) unsigned short sBh[128 * 32];
  __shared__ __align__(16) unsigned short sAl[SPLIT ? 128 * 32 : 8];
  __shared__ __align__(16) unsigned short sBl[SPLIT ? 128 * 32 : 8];

  const int tid = threadIdx.x;
  const int m0 = blockIdx.y * 128;
  const int n0 = blockIdx.x * 128;
  const int wave = tid >> 6;
  const int lane = tid & 63;
  const int wm = wave >> 1;
  const int wn = wave & 1;
  const int n15 = lane & 15;
  const int quad = lane >> 4;

  // staging decode: op j covers rows j*16..j*16+15, lane -> (srow, cpp)
  const int srow = lane >> 2;
  const int scp = lane & 3;
  const int cpl = scp ^ (srow >> 2);  // ((row>>2)&3) == (srow>>2) for row=j*16+srow

  floatx4 acc[4][4];
#pragma unroll
  for (int i = 0; i < 4; ++i)
#pragma unroll
    for (int j = 0; j < 4; ++j) acc[i][j] = (floatx4){0.f, 0.f, 0.f, 0.f};

  for (int k0 = 0; k0 < K; k0 += 32) {
    __syncthreads();  // all waves done reading previous tile
#pragma unroll
    for (int jj = 0; jj < 2; ++jj) {
      const int j = wave * 2 + jj;
      const int row = j * 16 + srow;
      const size_t goffA = (size_t)(m0 + row) * K + k0 + cpl * 8;
      const size_t goffB = (size_t)(n0 + row) * K + k0 + cpl * 8;
      gload16(Ahg + goffA, &sAh[j * 512]);
      gload16(Bhg + goffB, &sBh[j * 512]);
      if constexpr (SPLIT) {
        gload16(Alg + goffA, &sAl[j * 512]);
        gload16(Blg + goffB, &sBl[j * 512]);
      }
    }
    __syncthreads();  // vmcnt(0) drained by compiler before barrier

    short8 afh[4], afl[4];
#pragma unroll
    for (int mt = 0; mt < 4; ++mt) {
      const int row = wm * 64 + mt * 16 + n15;
      const int off = row * 32 + ((quad ^ (n15 >> 2)) << 3);
      afh[mt] = *(const short8*)&sAh[off];
      if constexpr (SPLIT) afl[mt] = *(const short8*)&sAl[off];
    }
#pragma unroll
    for (int nt = 0; nt < 4; ++nt) {
      const int row = wn * 64 + nt * 16 + n15;
      const int off = row * 32 + ((quad ^ (n15 >> 2)) << 3);
      const short8 bfh = *(const short8*)&sBh[off];
      if constexpr (SPLIT) {
        const short8 bfl = *(const short8*)&sBl[off];
#pragma unroll
        for (int mt = 0; mt < 4; ++mt) {
          acc[mt][nt] = __builtin_amdgcn_mfma_f32_16x16x32_bf16(afh[mt], bfh, acc[mt][nt], 0, 0, 0);
          acc[mt][nt] = __builtin_amdgcn_mfma_f32_16x16x32_bf16(afh[mt], bfl, acc[mt][nt], 0, 0, 0);
          acc[mt][nt] = __builtin_amdgcn_mfma_f32_16x16x32_bf16(afl[mt], bfh, acc[mt][nt], 0, 0, 0);
        }
      } else {
#pragma unroll
        for (int mt = 0; mt < 4; ++mt)
          acc[mt][nt] = __builtin_amdgcn_mfma_f32_16x16x32_bf16(afh[mt], bfh, acc[mt][nt], 0, 0, 0);
      }
    }
  }

#pragma unroll
  for (int mt = 0; mt < 4; ++mt) {
    float scalev[4] = {1.f, 1.f, 1.f, 1.f};
    if constexpr (L2N) {
#pragma unroll
      for (int rr = 0; rr < 4; ++rr) {
        float ss = 0.f;
#pragma unroll
        for (int nt = 0; nt < 4; ++nt) ss += acc[mt][nt][rr] * acc[mt][nt][rr];
        ss += __shfl_xor(ss, 1, 64);
        ss += __shfl_xor(ss, 2, 64);
        ss += __shfl_xor(ss, 4, 64);
        ss += __shfl_xor(ss, 8, 64);
        scalev[rr] = 1.0f / fmaxf(sqrtf(ss), 1e-12f);
      }
    }
#pragma unroll
    for (int nt = 0; nt < 4; ++nt) {
#pragma unroll
      for (int rr = 0; rr < 4; ++rr) {
        const int row = m0 + wm * 64 + mt * 16 + quad * 4 + rr;
        const int col = n0 + wn * 64 + nt * 16 + n15;
        const float v = acc[mt][nt][rr] * scalev[rr];
        if constexpr (F32OUT)
          ((float*)Cv)[(size_t)row * N + col] = v;
        else
          ((unsigned short*)Cv)[(size_t)row * N + col] = f2bf(v);
      }
    }
  }
}

// ---------------------------------------------------------------------------
// MFMA bf16 attention with register-prefetch pipeline (UNCHANGED from R5).
// ---------------------------------------------------------------------------
#define KC 128
#define KSPLIT 2
#define NCH (B2 / KSPLIT / KC)  // 32
#define PSTR 68

__global__ __launch_bounds__(256, 3) void attn_mfma(
    const unsigned short* __restrict__ qb,   // [B1][768] bf16, normalized
    const unsigned short* __restrict__ kb,   // [B2][768] bf16, normalized
    const unsigned short* __restrict__ vt,   // [768][B2] bf16 (v transposed)
    float* __restrict__ aoacc,               // [B1][768] f32, zeroed
    float* __restrict__ lacc,                // [B1][NH] f32, zeroed
    const int* __restrict__ invt_p) {
  __shared__ __align__(16) unsigned short smem[25088];  // 50176 B
  unsigned short* Kl = smem;            // [128 keys][64 d] swizzled, 16 KB
  unsigned short* Vl = smem + 8192;     // [64 d][128 keys] swizzled, 16 KB
  unsigned short* Psl = smem + 16384;   // 4 waves x [32 q][PSTR], 17.4 KB

  const float c2 = (float)invt_p[0] * 1.4426950408889634f;  // invt*log2(e)
  const int h = blockIdx.y;
  const int q0 = blockIdx.x * 64;
  const int tid = threadIdx.x;
  const int wave = tid >> 6;
  const int lane = tid & 63;
  const int qsub = wave >> 1;
  const int ksub = wave & 1;
  const int n15 = lane & 15;
  const int quad = lane >> 4;
  const int kz0 = blockIdx.z * (B2 / KSPLIT);

  unsigned short* Ps = &Psl[wave * 32 * PSTR];

  short8 qf[2][2];
#pragma unroll
  for (int qt = 0; qt < 2; ++qt)
#pragma unroll
    for (int ks = 0; ks < 2; ++ks) {
      const int qrow = q0 + qsub * 32 + qt * 16 + n15;
      qf[qt][ks] = *(const short8*)&qb[(size_t)qrow * DMODEL + h * DH + ks * 32 + quad * 8];
    }

  floatx4 oacc[2][4];
#pragma unroll
  for (int qt = 0; qt < 2; ++qt)
#pragma unroll
    for (int nt = 0; nt < 4; ++nt) oacc[qt][nt] = (floatx4){0.f, 0.f, 0.f, 0.f};
  float lsum[2] = {0.f, 0.f};

  ushort8 kr[4], vr[4];
#pragma unroll
  for (int i = 0; i < 4; ++i) {
    const int s = i * 256 + tid;
    const int key = s >> 3, cpk = s & 7, chk = cpk ^ (key & 7);
    kr[i] = *(const ushort8*)&kb[(size_t)(kz0 + key) * DMODEL + h * DH + chk * 8];
    const int d = s >> 4, cpv = s & 15, chv = cpv ^ (d & 15);
    vr[i] = *(const ushort8*)&vt[(size_t)(h * DH + d) * B2 + kz0 + chv * 8];
  }

  for (int c = 0; c < NCH; ++c) {
    __syncthreads();
#pragma unroll
    for (int i = 0; i < 4; ++i) {
      const int s = i * 256 + tid;
      const int key = s >> 3, cpk = s & 7;
      *(ushort8*)&Kl[key * 64 + cpk * 8] = kr[i];
      const int d = s >> 4, cpv = s & 15;
      *(ushort8*)&Vl[d * 128 + cpv * 8] = vr[i];
    }
    if (c + 1 < NCH) {
      const int kc0n = kz0 + (c + 1) * KC;
#pragma unroll
      for (int i = 0; i < 4; ++i) {
        const int s = i * 256 + tid;
        const int key = s >> 3, cpk = s & 7, chk = cpk ^ (key & 7);
        kr[i] = *(const ushort8*)&kb[(size_t)(kc0n + key) * DMODEL + h * DH + chk * 8];
        const int d = s >> 4, cpv = s & 15, chv = cpv ^ (d & 15);
        vr[i] = *(const ushort8*)&vt[(size_t)(h * DH + d) * B2 + kc0n + chv * 8];
      }
    }
    __syncthreads();

#pragma unroll
    for (int kt = 0; kt < 4; ++kt) {
      floatx4 s0 = {0.f, 0.f, 0.f, 0.f}, s1 = {0.f, 0.f, 0.f, 0.f};
#pragma unroll
      for (int ks = 0; ks < 2; ++ks) {
        const int key = ksub * 64 + kt * 16 + n15;
        const int cp = (ks * 4 + quad) ^ (n15 & 7);
        const short8 kf = *(const short8*)&Kl[key * 64 + cp * 8];
        s0 = __builtin_amdgcn_mfma_f32_16x16x32_bf16(kf, qf[0][ks], s0, 0, 0, 0);
        s1 = __builtin_amdgcn_mfma_f32_16x16x32_bf16(kf, qf[1][ks], s1, 0, 0, 0);
      }
      ushort4v p0, p1;
#pragma unroll
      for (int r = 0; r < 4; ++r) {
        const float e0 = exp2f(fmaf(s0[r], c2, -c2));
        const float e1 = exp2f(fmaf(s1[r], c2, -c2));
        lsum[0] += e0;
        lsum[1] += e1;
        p0[r] = f2bf(e0);
        p1[r] = f2bf(e1);
      }
      *(ushort4v*)&Ps[(0 * 16 + n15) * PSTR + kt * 16 + quad * 4] = p0;
      *(ushort4v*)&Ps[(1 * 16 + n15) * PSTR + kt * 16 + quad * 4] = p1;
    }

#pragma unroll
    for (int ks = 0; ks < 2; ++ks) {
      short8 pa[2];
#pragma unroll
      for (int qt = 0; qt < 2; ++qt)
        pa[qt] = *(const short8*)&Ps[(qt * 16 + n15) * PSTR + ks * 32 + quad * 8];
#pragma unroll
      for (int nt = 0; nt < 4; ++nt) {
        const int dd = nt * 16 + n15;
        const int cp = (ksub * 8 + ks * 4 + quad) ^ (n15 & 15);
        const short8 vf = *(const short8*)&Vl[dd * 128 + cp * 8];
        oacc[0][nt] = __builtin_amdgcn_mfma_f32_16x16x32_bf16(pa[0], vf, oacc[0][nt], 0, 0, 0);
        oacc[1][nt] = __builtin_amdgcn_mfma_f32_16x16x32_bf16(pa[1], vf, oacc[1][nt], 0, 0, 0);
      }
    }
  }

#pragma unroll
  for (int qt = 0; qt < 2; ++qt) {
    float v = lsum[qt];
    v += __shfl_xor(v, 16, 64);
    v += __shfl_xor(v, 32, 64);
    lsum[qt] = v;
  }
  if (quad == 0) {
#pragma unroll
    for (int qt = 0; qt < 2; ++qt)
      atomicAdd(&lacc[(q0 + qsub * 32 + qt * 16 + n15) * NH + h], lsum[qt]);
  }

  __syncthreads();
  float* Osc = (float*)smem;
  if (ksub == 1) {
#pragma unroll
    for (int qt = 0; qt < 2; ++qt)
#pragma unroll
      for (int nt = 0; nt < 4; ++nt)
#pragma unroll
        for (int r = 0; r < 4; ++r) {
          const int row = qsub * 32 + qt * 16 + quad * 4 + r;
          Osc[row * 64 + nt * 16 + n15] = oacc[qt][nt][r];
        }
  }
  __syncthreads();
  if (ksub == 0) {
#pragma unroll
    for (int qt = 0; qt < 2; ++qt)
#pragma unroll
      for (int nt = 0; nt < 4; ++nt)
#pragma unroll
        for (int r = 0; r < 4; ++r) {
          const int row = qsub * 32 + qt * 16 + quad * 4 + r;
          const float v = oacc[qt][nt][r] + Osc[row * 64 + nt * 16 + n15];
          atomicAdd(&aoacc[(size_t)(q0 + row) * DMODEL + h * DH + nt * 16 + n15], v);
        }
  }
}

// ---------------------------------------------------------------------------
// out_bf[q][h*64+d] = bf16( aoacc[q][h*64+d] / lacc[q][h] )
// ---------------------------------------------------------------------------
__global__ __launch_bounds__(256) void ao_normalize_bf(
    const float* __restrict__ ao, const float* __restrict__ l,
    unsigned short* __restrict__ out) {
  const int row = blockIdx.x;
  const int t = threadIdx.x;
#pragma unroll
  for (int i = 0; i < 3; ++i) {
    const int d = t + i * 256;
    out[(size_t)row * DMODEL + d] =
        f2bf(ao[(size_t)row * DMODEL + d] / l[row * NH + (d >> 6)]);
  }
}

// ---------------------------------------------------------------------------
__global__ __launch_bounds__(256) void l2norm_rows768_out(
    const float* __restrict__ x, float* __restrict__ out) {
  const int row = blockIdx.x;
  const float* xr = &x[(size_t)row * DMODEL];
  float ss = 0.0f;
  float vals[3];
#pragma unroll
  for (int i = 0; i < 3; ++i) {
    vals[i] = xr[threadIdx.x + i * 256];
    ss += vals[i] * vals[i];
  }
#pragma unroll
  for (int off = 32; off > 0; off >>= 1) ss += __shfl_xor(ss, off, 64);
  __shared__ float ws[4];
  if ((threadIdx.x & 63) == 0) ws[threadIdx.x >> 6] = ss;
  __syncthreads();
  const float tot = ws[0] + ws[1] + ws[2] + ws[3];
  const float sc = 1.0f / fmaxf(sqrtf(tot), 1e-12f);
  float* orow = &out[(size_t)row * DMODEL];
#pragma unroll
  for (int i = 0; i < 3; ++i) orow[threadIdx.x + i * 256] = vals[i] * sc;
}

// ---------------------------------------------------------------------------
extern "C" void kernel_launch(void* const* d_in, const int* in_sizes, int n_in,
                              void* d_out, int out_size, void* d_ws,
                              size_t ws_size, hipStream_t stream) {
  const float* x1 = (const float*)d_in[0];
  const float* x2 = (const float*)d_in[1];
  const float* Wq = (const float*)d_in[2];
  const float* Wk = (const float*)d_in[3];
  const float* Wv = (const float*)d_in[4];
  const float* Wo = (const float*)d_in[5];
  const int* invt = (const int*)d_in[6];
  float* outp = (float*)d_out;

  // workspace layout (bytes). Lifetime-based aliasing:
  //  - x1h/x1l dead after q-proj  -> aoacc (f32) reuses [0, 6291456)
  //  - x2l dead after k-proj      -> vt_bf reuses its region
  //  - x2h dead after v-proj      -> ao_bf + woout + lacc reuse its region
  char* ws = (char*)d_ws;
  unsigned short* x1h = (unsigned short*)(ws + 0);         // 3145728 B
  unsigned short* x1l = (unsigned short*)(ws + 3145728);   // 3145728 B
  unsigned short* x2h = (unsigned short*)(ws + 6291456);   // 12582912 B
  unsigned short* x2l = (unsigned short*)(ws + 18874368);  // 12582912 B
  unsigned short* Wqh = (unsigned short*)(ws + 31457280);  // 1179648 B
  unsigned short* Wql = (unsigned short*)(ws + 32636928);
  unsigned short* Wkh = (unsigned short*)(ws + 33816576);
  unsigned short* Wkl = (unsigned short*)(ws + 34996224);
  unsigned short* Wvh = (unsigned short*)(ws + 36175872);
  unsigned short* Woh = (unsigned short*)(ws + 37355520);
  unsigned short* q_bf = (unsigned short*)(ws + 38535168);  // 3145728 B
  unsigned short* k_bf = (unsigned short*)(ws + 41680896);  // 12582912 B  end 54263808
  // aliases:
  float* aoacc = (float*)(ws + 0);                          // 6291456 B (x1 region)
  unsigned short* vt_bf = (unsigned short*)(ws + 18874368); // 12582912 B (x2l region)
  unsigned short* ao_bf = (unsigned short*)(ws + 6291456);  // 3145728 B (x2h region)
  float* woout = (float*)(ws + 9437184);                    // 6291456 B (x2h region)
  float* lacc = (float*)(ws + 15728640);                    // 98304 B  (x2h region)

  // --- prep: one-time fp32 -> bf16 hi/lo splits ---
  split_hl<<<1536, 256, 0, stream>>>(x1, x1h, x1l, B1 * DMODEL);
  split_hl<<<6144, 256, 0, stream>>>(x2, x2h, x2l, B2 * DMODEL);
  split_hl<<<576, 256, 0, stream>>>(Wq, Wqh, Wql, DMODEL * DMODEL);
  split_hl<<<576, 256, 0, stream>>>(Wk, Wkh, Wkl, DMODEL * DMODEL);
  cvt_h<<<576, 256, 0, stream>>>(Wv, Wvh, DMODEL * DMODEL);
  cvt_h<<<576, 256, 0, stream>>>(Wo, Woh, DMODEL * DMODEL);

  // --- projections (all-bf16 MFMA GEMMs, global_load_lds staging) ---
  // q: split + fused per-head l2norm
  gemm_bf16_nt<true, true, false><<<dim3(6, 16), 256, 0, stream>>>(
      x1h, x1l, Wqh, Wql, q_bf, B1, DMODEL, DMODEL);
  // k: split + fused per-head l2norm
  gemm_bf16_nt<true, true, false><<<dim3(6, 64), 256, 0, stream>>>(
      x2h, x2l, Wkh, Wkl, k_bf, B2, DMODEL, DMODEL);
  // v transposed: vt = Wv @ x2^T (plain; writes x2l region, reads x2h)
  gemm_bf16_nt<false, false, false><<<dim3(64, 6), 256, 0, stream>>>(
      Wvh, nullptr, x2h, nullptr, vt_bf, DMODEL, B2, DMODEL);

  // zero accumulators (after q-proj/v-proj: regions alias x1 and x2h)
  hipMemsetAsync(aoacc, 0, (size_t)B1 * DMODEL * sizeof(float), stream);
  hipMemsetAsync(lacc, 0, (size_t)B1 * NH * sizeof(float), stream);

  // attention (unchanged R5 kernel)
  attn_mfma<<<dim3(B1 / 64, NH, KSPLIT), 256, 0, stream>>>(q_bf, k_bf, vt_bf,
                                                           aoacc, lacc, invt);
  ao_normalize_bf<<<B1, 256, 0, stream>>>(aoacc, lacc, ao_bf);
  // output projection: plain bf16, f32 out
  gemm_bf16_nt<false, false, true><<<dim3(6, 16), 256, 0, stream>>>(
      ao_bf, nullptr, Woh, nullptr, woout, B1, DMODEL, DMODEL);
  l2norm_rows768_out<<<B1, 256, 0, stream>>>(woout, outp);
}

// Round 7
// 308.351 us; speedup vs baseline: 1.3310x; 1.1434x over previous
//
#include <hip/hip_runtime.h>
#include <hip/hip_bf16.h>
#include <math.h>

#define B1 2048
#define B2 8192
#define NH 12
#define DH 64
#define DMODEL 768

typedef __attribute__((ext_vector_type(8))) short short8;
typedef __attribute__((ext_vector_type(4))) float floatx4;
typedef __attribute__((ext_vector_type(8))) unsigned short ushort8;
typedef __attribute__((ext_vector_type(4))) unsigned short ushort4v;

static __device__ __forceinline__ unsigned short f2bf(float f) {
  __bf16 b = (__bf16)f;
  return __builtin_bit_cast(unsigned short, b);
}
static __device__ __forceinline__ float bf2f(unsigned short u) {
  return __builtin_bit_cast(float, ((unsigned)u) << 16);
}

// async global->LDS, 16B per lane; LDS dest = wave-uniform base + lane*16
static __device__ __forceinline__ void gload16(const unsigned short* g,
                                               unsigned short* l) {
  __builtin_amdgcn_global_load_lds(
      (const __attribute__((address_space(1))) void*)g,
      (__attribute__((address_space(3))) void*)l, 16, 0, 0);
}

// ---------------------------------------------------------------------------
// Fused prep: ALL fp32 -> bf16 hi/lo splits + hi-only converts, one launch.
// block-role table: [0,1536) x1 | [1536,7680) x2 | [7680,8256) Wq |
// [8256,8832) Wk | [8832,9408) Wv(hi only) | [9408,9984) Wo(hi only)
// ---------------------------------------------------------------------------
__global__ __launch_bounds__(256) void prep_all(
    const float* __restrict__ x1, unsigned short* __restrict__ x1h,
    unsigned short* __restrict__ x1l, const float* __restrict__ x2,
    unsigned short* __restrict__ x2h, unsigned short* __restrict__ x2l,
    const float* __restrict__ Wq, unsigned short* __restrict__ Wqh,
    unsigned short* __restrict__ Wql, const float* __restrict__ Wk,
    unsigned short* __restrict__ Wkh, unsigned short* __restrict__ Wkl,
    const float* __restrict__ Wv, unsigned short* __restrict__ Wvh,
    const float* __restrict__ Wo, unsigned short* __restrict__ Woh) {
  const int bi = blockIdx.x;
  const float* src;
  unsigned short *hi, *lo = nullptr;
  int lb;
  if (bi < 1536) {
    src = x1; hi = x1h; lo = x1l; lb = bi;
  } else if (bi < 7680) {
    src = x2; hi = x2h; lo = x2l; lb = bi - 1536;
  } else if (bi < 8256) {
    src = Wq; hi = Wqh; lo = Wql; lb = bi - 7680;
  } else if (bi < 8832) {
    src = Wk; hi = Wkh; lo = Wkl; lb = bi - 8256;
  } else if (bi < 9408) {
    src = Wv; hi = Wvh; lb = bi - 8832;
  } else {
    src = Wo; hi = Woh; lb = bi - 9408;
  }
  const int i = (lb * 256 + threadIdx.x) * 4;
  const float4 v = *(const float4*)&src[i];
  ushort4v h = {f2bf(v.x), f2bf(v.y), f2bf(v.z), f2bf(v.w)};
  *(ushort4v*)&hi[i] = h;
  if (lo) {
    ushort4v l = {f2bf(v.x - bf2f(h[0])), f2bf(v.y - bf2f(h[1])),
                  f2bf(v.z - bf2f(h[2])), f2bf(v.w - bf2f(h[3]))};
    *(ushort4v*)&lo[i] = l;
  }
}

// ---------------------------------------------------------------------------
// Core bf16 MFMA GEMM tile: C[M,N] = A[M,K]*B[N,K]^T (both K-contiguous).
// 128x128 tile, BK=32, 4 waves (2x2), 64x64/wave, global_load_lds staging,
// XOR-swizzled granules (swizzle on GLOBAL addr; frag reads 2-way = free).
// SPLIT: hi/lo 3-MFMA k-step (~fp32). L2N: per-64-col L2 norm epilogue.
// ---------------------------------------------------------------------------
template <bool SPLIT, bool L2N, bool F32OUT>
static __device__ __forceinline__ void gemm_tile(
    const unsigned short* __restrict__ Ahg, const unsigned short* __restrict__ Alg,
    const unsigned short* __restrict__ Bhg, const unsigned short* __restrict__ Blg,
    void* __restrict__ Cv, int M, int N, int K, int m0, int n0,
    unsigned short* sAh, unsigned short* sBh, unsigned short* sAl,
    unsigned short* sBl) {
  const int tid = threadIdx.x;
  const int wave = tid >> 6;
  const int lane = tid & 63;
  const int wm = wave >> 1;
  const int wn = wave & 1;
  const int n15 = lane & 15;
  const int quad = lane >> 4;
  const int srow = lane >> 2;
  const int cpl = (lane & 3) ^ (srow >> 2);

  floatx4 acc[4][4];
#pragma unroll
  for (int i = 0; i < 4; ++i)
#pragma unroll
    for (int j = 0; j < 4; ++j) acc[i][j] = (floatx4){0.f, 0.f, 0.f, 0.f};

  for (int k0 = 0; k0 < K; k0 += 32) {
    __syncthreads();
#pragma unroll
    for (int jj = 0; jj < 2; ++jj) {
      const int j = wave * 2 + jj;
      const int row = j * 16 + srow;
      const size_t goffA = (size_t)(m0 + row) * K + k0 + cpl * 8;
      const size_t goffB = (size_t)(n0 + row) * K + k0 + cpl * 8;
      gload16(Ahg + goffA, &sAh[j * 512]);
      gload16(Bhg + goffB, &sBh[j * 512]);
      if constexpr (SPLIT) {
        gload16(Alg + goffA, &sAl[j * 512]);
        gload16(Blg + goffB, &sBl[j * 512]);
      }
    }
    __syncthreads();

    short8 afh[4], afl[4];
#pragma unroll
    for (int mt = 0; mt < 4; ++mt) {
      const int row = wm * 64 + mt * 16 + n15;
      const int off = row * 32 + ((quad ^ (n15 >> 2)) << 3);
      afh[mt] = *(const short8*)&sAh[off];
      if constexpr (SPLIT) afl[mt] = *(const short8*)&sAl[off];
    }
#pragma unroll
    for (int nt = 0; nt < 4; ++nt) {
      const int row = wn * 64 + nt * 16 + n15;
      const int off = row * 32 + ((quad ^ (n15 >> 2)) << 3);
      const short8 bfh = *(const short8*)&sBh[off];
      if constexpr (SPLIT) {
        const short8 bfl = *(const short8*)&sBl[off];
#pragma unroll
        for (int mt = 0; mt < 4; ++mt) {
          acc[mt][nt] = __builtin_amdgcn_mfma_f32_16x16x32_bf16(afh[mt], bfh, acc[mt][nt], 0, 0, 0);
          acc[mt][nt] = __builtin_amdgcn_mfma_f32_16x16x32_bf16(afh[mt], bfl, acc[mt][nt], 0, 0, 0);
          acc[mt][nt] = __builtin_amdgcn_mfma_f32_16x16x32_bf16(afl[mt], bfh, acc[mt][nt], 0, 0, 0);
        }
      } else {
#pragma unroll
        for (int mt = 0; mt < 4; ++mt)
          acc[mt][nt] = __builtin_amdgcn_mfma_f32_16x16x32_bf16(afh[mt], bfh, acc[mt][nt], 0, 0, 0);
      }
    }
  }

#pragma unroll
  for (int mt = 0; mt < 4; ++mt) {
    float scalev[4] = {1.f, 1.f, 1.f, 1.f};
    if constexpr (L2N) {
#pragma unroll
      for (int rr = 0; rr < 4; ++rr) {
        float ss = 0.f;
#pragma unroll
        for (int nt = 0; nt < 4; ++nt) ss += acc[mt][nt][rr] * acc[mt][nt][rr];
        ss += __shfl_xor(ss, 1, 64);
        ss += __shfl_xor(ss, 2, 64);
        ss += __shfl_xor(ss, 4, 64);
        ss += __shfl_xor(ss, 8, 64);
        scalev[rr] = 1.0f / fmaxf(sqrtf(ss), 1e-12f);
      }
    }
#pragma unroll
    for (int nt = 0; nt < 4; ++nt) {
#pragma unroll
      for (int rr = 0; rr < 4; ++rr) {
        const int row = m0 + wm * 64 + mt * 16 + quad * 4 + rr;
        const int col = n0 + wn * 64 + nt * 16 + n15;
        const float v = acc[mt][nt][rr] * scalev[rr];
        if constexpr (F32OUT)
          ((float*)Cv)[(size_t)row * N + col] = v;
        else
          ((unsigned short*)Cv)[(size_t)row * N + col] = f2bf(v);
      }
    }
  }
}

// ---------------------------------------------------------------------------
// Fused q-proj + k-proj (both SPLIT + per-head L2N, bf16 out). 480 blocks.
// ---------------------------------------------------------------------------
__global__ __launch_bounds__(256) void qk_proj(
    const unsigned short* __restrict__ x1h, const unsigned short* __restrict__ x1l,
    const unsigned short* __restrict__ Wqh, const unsigned short* __restrict__ Wql,
    const unsigned short* __restrict__ x2h, const unsigned short* __restrict__ x2l,
    const unsigned short* __restrict__ Wkh, const unsigned short* __restrict__ Wkl,
    unsigned short* __restrict__ qbf, unsigned short* __restrict__ kbf) {
  __shared__ __align__(16) unsigned short sAh[4096], sBh[4096], sAl[4096], sBl[4096];
  const int bi = blockIdx.x;
  if (bi < 96) {
    gemm_tile<true, true, false>(x1h, x1l, Wqh, Wql, qbf, B1, DMODEL, DMODEL,
                                 (bi / 6) * 128, (bi % 6) * 128, sAh, sBh, sAl, sBl);
  } else {
    const int b = bi - 96;
    gemm_tile<true, true, false>(x2h, x2l, Wkh, Wkl, kbf, B2, DMODEL, DMODEL,
                                 (b / 6) * 128, (b % 6) * 128, sAh, sBh, sAl, sBl);
  }
}

// ---------------------------------------------------------------------------
// Fused v-proj (vt = Wv @ x2^T, plain bf16) + zero aoacc + zero lacc.
// roles: [0,384) v-proj | [384,768) zero aoacc | [768,774) zero lacc.
// ---------------------------------------------------------------------------
__global__ __launch_bounds__(256) void v_zero(
    const unsigned short* __restrict__ Wvh, const unsigned short* __restrict__ x2h,
    unsigned short* __restrict__ vtbf, float* __restrict__ aoacc,
    float* __restrict__ lacc) {
  __shared__ __align__(16) unsigned short sAh[4096], sBh[4096];
  const int bi = blockIdx.x;
  if (bi < 384) {
    gemm_tile<false, false, false>(Wvh, nullptr, x2h, nullptr, vtbf, DMODEL, B2,
                                   DMODEL, (bi / 64) * 128, (bi % 64) * 128,
                                   sAh, sBh, nullptr, nullptr);
  } else if (bi < 768) {
    const float4 z = {0.f, 0.f, 0.f, 0.f};
    float4* p = (float4*)aoacc + (size_t)(bi - 384) * 1024 + threadIdx.x;
    p[0] = z; p[256] = z; p[512] = z; p[768] = z;
  } else {
    const float4 z = {0.f, 0.f, 0.f, 0.f};
    float4* p = (float4*)lacc + (size_t)(bi - 768) * 1024 + threadIdx.x;
    p[0] = z; p[256] = z; p[512] = z; p[768] = z;
  }
}

// ---------------------------------------------------------------------------
// MFMA bf16 attention with register-prefetch pipeline (UNCHANGED from R5).
// ---------------------------------------------------------------------------
#define KC 128
#define KSPLIT 2
#define NCH (B2 / KSPLIT / KC)  // 32
#define PSTR 68

__global__ __launch_bounds__(256, 3) void attn_mfma(
    const unsigned short* __restrict__ qb, const unsigned short* __restrict__ kb,
    const unsigned short* __restrict__ vt, float* __restrict__ aoacc,
    float* __restrict__ lacc, const int* __restrict__ invt_p) {
  __shared__ __align__(16) unsigned short smem[25088];  // 50176 B
  unsigned short* Kl = smem;
  unsigned short* Vl = smem + 8192;
  unsigned short* Psl = smem + 16384;

  const float c2 = (float)invt_p[0] * 1.4426950408889634f;
  const int h = blockIdx.y;
  const int q0 = blockIdx.x * 64;
  const int tid = threadIdx.x;
  const int wave = tid >> 6;
  const int lane = tid & 63;
  const int qsub = wave >> 1;
  const int ksub = wave & 1;
  const int n15 = lane & 15;
  const int quad = lane >> 4;
  const int kz0 = blockIdx.z * (B2 / KSPLIT);

  unsigned short* Ps = &Psl[wave * 32 * PSTR];

  short8 qf[2][2];
#pragma unroll
  for (int qt = 0; qt < 2; ++qt)
#pragma unroll
    for (int ks = 0; ks < 2; ++ks) {
      const int qrow = q0 + qsub * 32 + qt * 16 + n15;
      qf[qt][ks] = *(const short8*)&qb[(size_t)qrow * DMODEL + h * DH + ks * 32 + quad * 8];
    }

  floatx4 oacc[2][4];
#pragma unroll
  for (int qt = 0; qt < 2; ++qt)
#pragma unroll
    for (int nt = 0; nt < 4; ++nt) oacc[qt][nt] = (floatx4){0.f, 0.f, 0.f, 0.f};
  float lsum[2] = {0.f, 0.f};

  ushort8 kr[4], vr[4];
#pragma unroll
  for (int i = 0; i < 4; ++i) {
    const int s = i * 256 + tid;
    const int key = s >> 3, cpk = s & 7, chk = cpk ^ (key & 7);
    kr[i] = *(const ushort8*)&kb[(size_t)(kz0 + key) * DMODEL + h * DH + chk * 8];
    const int d = s >> 4, cpv = s & 15, chv = cpv ^ (d & 15);
    vr[i] = *(const ushort8*)&vt[(size_t)(h * DH + d) * B2 + kz0 + chv * 8];
  }

  for (int c = 0; c < NCH; ++c) {
    __syncthreads();
#pragma unroll
    for (int i = 0; i < 4; ++i) {
      const int s = i * 256 + tid;
      const int key = s >> 3, cpk = s & 7;
      *(ushort8*)&Kl[key * 64 + cpk * 8] = kr[i];
      const int d = s >> 4, cpv = s & 15;
      *(ushort8*)&Vl[d * 128 + cpv * 8] = vr[i];
    }
    if (c + 1 < NCH) {
      const int kc0n = kz0 + (c + 1) * KC;
#pragma unroll
      for (int i = 0; i < 4; ++i) {
        const int s = i * 256 + tid;
        const int key = s >> 3, cpk = s & 7, chk = cpk ^ (key & 7);
        kr[i] = *(const ushort8*)&kb[(size_t)(kc0n + key) * DMODEL + h * DH + chk * 8];
        const int d = s >> 4, cpv = s & 15, chv = cpv ^ (d & 15);
        vr[i] = *(const ushort8*)&vt[(size_t)(h * DH + d) * B2 + kc0n + chv * 8];
      }
    }
    __syncthreads();

#pragma unroll
    for (int kt = 0; kt < 4; ++kt) {
      floatx4 s0 = {0.f, 0.f, 0.f, 0.f}, s1 = {0.f, 0.f, 0.f, 0.f};
#pragma unroll
      for (int ks = 0; ks < 2; ++ks) {
        const int key = ksub * 64 + kt * 16 + n15;
        const int cp = (ks * 4 + quad) ^ (n15 & 7);
        const short8 kf = *(const short8*)&Kl[key * 64 + cp * 8];
        s0 = __builtin_amdgcn_mfma_f32_16x16x32_bf16(kf, qf[0][ks], s0, 0, 0, 0);
        s1 = __builtin_amdgcn_mfma_f32_16x16x32_bf16(kf, qf[1][ks], s1, 0, 0, 0);
      }
      ushort4v p0, p1;
#pragma unroll
      for (int r = 0; r < 4; ++r) {
        const float e0 = exp2f(fmaf(s0[r], c2, -c2));
        const float e1 = exp2f(fmaf(s1[r], c2, -c2));
        lsum[0] += e0;
        lsum[1] += e1;
        p0[r] = f2bf(e0);
        p1[r] = f2bf(e1);
      }
      *(ushort4v*)&Ps[(0 * 16 + n15) * PSTR + kt * 16 + quad * 4] = p0;
      *(ushort4v*)&Ps[(1 * 16 + n15) * PSTR + kt * 16 + quad * 4] = p1;
    }

#pragma unroll
    for (int ks = 0; ks < 2; ++ks) {
      short8 pa[2];
#pragma unroll
      for (int qt = 0; qt < 2; ++qt)
        pa[qt] = *(const short8*)&Ps[(qt * 16 + n15) * PSTR + ks * 32 + quad * 8];
#pragma unroll
      for (int nt = 0; nt < 4; ++nt) {
        const int dd = nt * 16 + n15;
        const int cp = (ksub * 8 + ks * 4 + quad) ^ (n15 & 15);
        const short8 vf = *(const short8*)&Vl[dd * 128 + cp * 8];
        oacc[0][nt] = __builtin_amdgcn_mfma_f32_16x16x32_bf16(pa[0], vf, oacc[0][nt], 0, 0, 0);
        oacc[1][nt] = __builtin_amdgcn_mfma_f32_16x16x32_bf16(pa[1], vf, oacc[1][nt], 0, 0, 0);
      }
    }
  }

#pragma unroll
  for (int qt = 0; qt < 2; ++qt) {
    float v = lsum[qt];
    v += __shfl_xor(v, 16, 64);
    v += __shfl_xor(v, 32, 64);
    lsum[qt] = v;
  }
  if (quad == 0) {
#pragma unroll
    for (int qt = 0; qt < 2; ++qt)
      atomicAdd(&lacc[(q0 + qsub * 32 + qt * 16 + n15) * NH + h], lsum[qt]);
  }

  __syncthreads();
  float* Osc = (float*)smem;
  if (ksub == 1) {
#pragma unroll
    for (int qt = 0; qt < 2; ++qt)
#pragma unroll
      for (int nt = 0; nt < 4; ++nt)
#pragma unroll
        for (int r = 0; r < 4; ++r) {
          const int row = qsub * 32 + qt * 16 + quad * 4 + r;
          Osc[row * 64 + nt * 16 + n15] = oacc[qt][nt][r];
        }
  }
  __syncthreads();
  if (ksub == 0) {
#pragma unroll
    for (int qt = 0; qt < 2; ++qt)
#pragma unroll
      for (int nt = 0; nt < 4; ++nt)
#pragma unroll
        for (int r = 0; r < 4; ++r) {
          const int row = qsub * 32 + qt * 16 + quad * 4 + r;
          const float v = oacc[qt][nt][r] + Osc[row * 64 + nt * 16 + n15];
          atomicAdd(&aoacc[(size_t)(q0 + row) * DMODEL + h * DH + nt * 16 + n15], v);
        }
  }
}

// ---------------------------------------------------------------------------
// Wo projection with FUSED ao-normalize in A-staging:
// A[row][col] = bf16( aoacc[row][col] / lacc[row][col>>6] ), B = Woh (gload16).
// C = f32 woout [B1, 768]. 96 blocks.
// ---------------------------------------------------------------------------
__global__ __launch_bounds__(256) void wo_proj(
    const float* __restrict__ aoacc, const float* __restrict__ lacc,
    const unsigned short* __restrict__ Woh, float* __restrict__ woout) {
  __shared__ __align__(16) unsigned short sAh[4096], sBh[4096];
  const int bi = blockIdx.x;
  const int m0 = (bi / 6) * 128;
  const int n0 = (bi % 6) * 128;
  const int tid = threadIdx.x;
  const int wave = tid >> 6;
  const int lane = tid & 63;
  const int wm = wave >> 1;
  const int wn = wave & 1;
  const int n15 = lane & 15;
  const int quad = lane >> 4;
  const int srow = lane >> 2;
  const int cpl = (lane & 3) ^ (srow >> 2);

  floatx4 acc[4][4];
#pragma unroll
  for (int i = 0; i < 4; ++i)
#pragma unroll
    for (int j = 0; j < 4; ++j) acc[i][j] = (floatx4){0.f, 0.f, 0.f, 0.f};

  for (int k0 = 0; k0 < DMODEL; k0 += 32) {
    __syncthreads();
#pragma unroll
    for (int jj = 0; jj < 2; ++jj) {
      const int j = wave * 2 + jj;
      const int row = j * 16 + srow;
      // A: load 8 f32 from aoacc, normalize, convert, ds_write 16B
      const size_t ga = (size_t)(m0 + row) * DMODEL + k0 + cpl * 8;
      const float4 a0 = *(const float4*)&aoacc[ga];
      const float4 a1 = *(const float4*)&aoacc[ga + 4];
      const int head = (k0 + cpl * 8) >> 6;
      const float inv = 1.0f / lacc[(m0 + row) * NH + head];
      ushort8 ah = {f2bf(a0.x * inv), f2bf(a0.y * inv), f2bf(a0.z * inv),
                    f2bf(a0.w * inv), f2bf(a1.x * inv), f2bf(a1.y * inv),
                    f2bf(a1.z * inv), f2bf(a1.w * inv)};
      *(ushort8*)&sAh[j * 512 + lane * 8] = ah;
      // B: async staging
      gload16(Woh + (size_t)(n0 + row) * DMODEL + k0 + cpl * 8, &sBh[j * 512]);
    }
    __syncthreads();

    short8 afh[4];
#pragma unroll
    for (int mt = 0; mt < 4; ++mt) {
      const int row = wm * 64 + mt * 16 + n15;
      afh[mt] = *(const short8*)&sAh[row * 32 + ((quad ^ (n15 >> 2)) << 3)];
    }
#pragma unroll
    for (int nt = 0; nt < 4; ++nt) {
      const int row = wn * 64 + nt * 16 + n15;
      const short8 bfh = *(const short8*)&sBh[row * 32 + ((quad ^ (n15 >> 2)) << 3)];
#pragma unroll
      for (int mt = 0; mt < 4; ++mt)
        acc[mt][nt] = __builtin_amdgcn_mfma_f32_16x16x32_bf16(afh[mt], bfh, acc[mt][nt], 0, 0, 0);
    }
  }

#pragma unroll
  for (int mt = 0; mt < 4; ++mt)
#pragma unroll
    for (int nt = 0; nt < 4; ++nt)
#pragma unroll
      for (int rr = 0; rr < 4; ++rr) {
        const int row = m0 + wm * 64 + mt * 16 + quad * 4 + rr;
        const int col = n0 + wn * 64 + nt * 16 + n15;
        woout[(size_t)row * DMODEL + col] = acc[mt][nt][rr];
      }
}

// ---------------------------------------------------------------------------
__global__ __launch_bounds__(256) void l2norm_rows768_out(
    const float* __restrict__ x, float* __restrict__ out) {
  const int row = blockIdx.x;
  const float* xr = &x[(size_t)row * DMODEL];
  float ss = 0.0f;
  float vals[3];
#pragma unroll
  for (int i = 0; i < 3; ++i) {
    vals[i] = xr[threadIdx.x + i * 256];
    ss += vals[i] * vals[i];
  }
#pragma unroll
  for (int off = 32; off > 0; off >>= 1) ss += __shfl_xor(ss, off, 64);
  __shared__ float ws[4];
  if ((threadIdx.x & 63) == 0) ws[threadIdx.x >> 6] = ss;
  __syncthreads();
  const float tot = ws[0] + ws[1] + ws[2] + ws[3];
  const float sc = 1.0f / fmaxf(sqrtf(tot), 1e-12f);
  float* orow = &out[(size_t)row * DMODEL];
#pragma unroll
  for (int i = 0; i < 3; ++i) orow[threadIdx.x + i * 256] = vals[i] * sc;
}

// ---------------------------------------------------------------------------
extern "C" void kernel_launch(void* const* d_in, const int* in_sizes, int n_in,
                              void* d_out, int out_size, void* d_ws,
                              size_t ws_size, hipStream_t stream) {
  const float* x1 = (const float*)d_in[0];
  const float* x2 = (const float*)d_in[1];
  const float* Wq = (const float*)d_in[2];
  const float* Wk = (const float*)d_in[3];
  const float* Wv = (const float*)d_in[4];
  const float* Wo = (const float*)d_in[5];
  const int* invt = (const int*)d_in[6];
  float* outp = (float*)d_out;

  // workspace (bytes). Aliases are lifetime-safe under stream serialization:
  //  aoacc  <- x1h/x1l region (x1* dead after qk_proj; zeroed in v_zero)
  //  vt_bf  <- x2l region (x2l dead after qk_proj)
  //  woout  <- inside x2h region (x2h dead after v_zero)
  //  lacc   <- own region after k_bf (zeroed in v_zero)
  char* ws = (char*)d_ws;
  unsigned short* x1h = (unsigned short*)(ws + 0);
  unsigned short* x1l = (unsigned short*)(ws + 3145728);
  unsigned short* x2h = (unsigned short*)(ws + 6291456);
  unsigned short* x2l = (unsigned short*)(ws + 18874368);
  unsigned short* Wqh = (unsigned short*)(ws + 31457280);
  unsigned short* Wql = (unsigned short*)(ws + 32636928);
  unsigned short* Wkh = (unsigned short*)(ws + 33816576);
  unsigned short* Wkl = (unsigned short*)(ws + 34996224);
  unsigned short* Wvh = (unsigned short*)(ws + 36175872);
  unsigned short* Woh = (unsigned short*)(ws + 37355520);
  unsigned short* q_bf = (unsigned short*)(ws + 38535168);
  unsigned short* k_bf = (unsigned short*)(ws + 41680896);
  float* lacc = (float*)(ws + 54263808);                     // end 54362112
  // aliases:
  float* aoacc = (float*)(ws + 0);
  unsigned short* vt_bf = (unsigned short*)(ws + 18874368);
  float* woout = (float*)(ws + 9437184);

  // 1) all prep in one launch
  prep_all<<<9984, 256, 0, stream>>>(x1, x1h, x1l, x2, x2h, x2l, Wq, Wqh, Wql,
                                     Wk, Wkh, Wkl, Wv, Wvh, Wo, Woh);
  // 2) q-proj + k-proj fused (split precision + per-head l2norm)
  qk_proj<<<480, 256, 0, stream>>>(x1h, x1l, Wqh, Wql, x2h, x2l, Wkh, Wkl,
                                   q_bf, k_bf);
  // 3) v-proj + zero accumulators fused
  v_zero<<<774, 256, 0, stream>>>(Wvh, x2h, vt_bf, aoacc, lacc);
  // 4) attention (unchanged)
  attn_mfma<<<dim3(B1 / 64, NH, KSPLIT), 256, 0, stream>>>(q_bf, k_bf, vt_bf,
                                                           aoacc, lacc, invt);
  // 5) Wo projection with fused ao-normalize staging
  wo_proj<<<96, 256, 0, stream>>>(aoacc, lacc, Woh, woout);
  // 6) final row l2norm
  l2norm_rows768_out<<<B1, 256, 0, stream>>>(woout, outp);
}